// Round 1
// baseline (284.379 us; speedup 1.0000x reference)
//
#include <hip/hip_runtime.h>

// CalculateSLayer: a = adj.sum(axis=2) (4096x4096), s_in = a^T @ s, s_out = a @ s
// Fused single pass over adj (134 MB, HBM floor ~21 us), bf16 MFMA, fp32 atomics
// for cross-block reduction. d_out = [s_in (4096x70) | s_out (4096x70)] fp32.

#define N    4096
#define D    70
#define DP   80          // d padded to 5 n-tiles of 16
#define TILE 128         // block tile (i) x (j)
#define NT_D 5

typedef short short8 __attribute__((ext_vector_type(8)));   // 8 x bf16 bits
typedef float f32x4  __attribute__((ext_vector_type(4)));

__device__ __forceinline__ unsigned short f2bf(float f) {
    // fp32 -> bf16, round-to-nearest-even
    unsigned u = __builtin_bit_cast(unsigned, f);
    u += 0x7FFFu + ((u >> 16) & 1u);
    return (unsigned short)(u >> 16);
}

// ---------------------------------------------------------------------------
// kernel0: sT[d][n] = bf16(s[n][d]) for d<70, zeros for 70<=d<80 (in d_ws).
// Makes MFMA B-operand staging a clean coalesced row copy in the main kernel.
// ---------------------------------------------------------------------------
__global__ __launch_bounds__(256) void build_sT(const float* __restrict__ s,
                                                unsigned short* __restrict__ sT) {
    __shared__ unsigned short tile[DP][264];   // pad 264: conflict-free columns
    const int t  = threadIdx.x;
    const int n0 = blockIdx.x * 256;
    #pragma unroll
    for (int d = 0; d < D; ++d)
        tile[d][t] = f2bf(s[(size_t)(n0 + t) * D + d]);
    __syncthreads();
    #pragma unroll
    for (int d = 0; d < DP; ++d) {
        unsigned short v = (d < D) ? tile[d][t] : (unsigned short)0;
        sT[(size_t)d * N + n0 + t] = v;        // coalesced 512B/wave stores
    }
}

// ---------------------------------------------------------------------------
// kernel1: per 128x128 tile of a, compute partial s_out (case 1, contract j)
// and partial s_in (case 2, contract i) with mfma_f32_16x16x32_bf16, then
// atomicAdd into d_out. j handled in 4 chunks of 32 to keep LDS < 64 KB.
// Layouts (verified, learn_hip m89/m120):
//   A-frag: A[m=lane&15][k=quad*8+j]   B-frag: B[k=quad*8+j][n=lane&15]
//   C/D   : col=lane&15, row=quad*4+reg
// ---------------------------------------------------------------------------
__global__ __launch_bounds__(512, 4) void fused_slayer(
    const float* __restrict__ adj,
    const unsigned short* __restrict__ sT,
    float* __restrict__ out_sin,    // d_out
    float* __restrict__ out_sout)   // d_out + N*D
{
    // pitches: a_row 40 (80B rows: b128-aligned, conflict-free b32 writes)
    //          aT/sT 136 (272B rows: b128-aligned; aT b16 transpose writes 8-way, cheap)
    __shared__ __align__(16) unsigned short a_row[TILE][40]; // [i][j_local<32]
    __shared__ __align__(16) unsigned short aTt[32][136];    // [j_local][i<128]
    __shared__ __align__(16) unsigned short sTi[DP][136];    // s rows for i-range
    __shared__ __align__(16) unsigned short sTj[DP][136];    // s rows for j-range

    const int t    = threadIdx.x;
    const int lane = t & 63;
    const int w    = t >> 6;       // wave 0..7
    const int l16  = lane & 15;
    const int q    = lane >> 4;    // quad 0..3

    const int I0 = blockIdx.y * TILE;
    const int J0 = blockIdx.x * TILE;

    // ---- stage both s-tiles (bf16 row copies from precomputed sT) ----
    {
        const int c  = t & 15;     // 16B chunk within 256B row
        const int rr = t >> 4;     // 0..31
        #pragma unroll
        for (int p = 0; p < 3; ++p) {
            int d = rr + 32 * p;
            if (d < DP) {
                uint4 vi = *(const uint4*)(sT + (size_t)d * N + I0 + 8 * c);
                uint4 vj = *(const uint4*)(sT + (size_t)d * N + J0 + 8 * c);
                *(uint4*)&sTi[d][8 * c] = vi;
                *(uint4*)&sTj[d][8 * c] = vj;
            }
        }
    }

    const f32x4 zero = {0.0f, 0.0f, 0.0f, 0.0f};
    f32x4 acc1[NT_D];
    #pragma unroll
    for (int nt = 0; nt < NT_D; ++nt) acc1[nt] = zero;

    // case-2 (s_in) per-chunk slot assignment: 10 slots = 2 m-tiles x 5 n-tiles,
    // wave w -> (mt2=w&1, nt=w>>1); waves 0,1 also take (mt2=w, nt=4).
    const int slot_mt = w & 1;
    const int slot_nt = w >> 1;
    const bool extra  = (w < 2);

    const int jp = t & 15;   // j-pair within 32-wide chunk (j_local = 2*jp)
    const int ir = t >> 4;   // 0..31

    for (int jc = 0; jc < 4; ++jc) {
        // issue global loads before the barrier (4-deep MLP per thread)
        float4 v[4];
        #pragma unroll
        for (int it = 0; it < 4; ++it) {
            int i = 32 * it + ir;
            v[it] = *(const float4*)(adj + (size_t)(I0 + i) * (2 * N)
                                         + (size_t)(J0 + 32 * jc + 2 * jp) * 2);
        }
        __syncthreads();   // previous chunk's LDS reads complete

        #pragma unroll
        for (int it = 0; it < 4; ++it) {
            int i = 32 * it + ir;
            unsigned short b0 = f2bf(v[it].x + v[it].y);   // a = ch0 + ch1
            unsigned short b1 = f2bf(v[it].z + v[it].w);
            *(unsigned int*)&a_row[i][2 * jp] =
                (unsigned int)b0 | ((unsigned int)b1 << 16);
            aTt[2 * jp][i]     = b0;   // transpose store (8-way b16, tolerable)
            aTt[2 * jp + 1][i] = b1;
        }
        __syncthreads();

        // ---- case 1: s_out += a_tile @ s_j   (this chunk = one 32-k step) ----
        {
            short8 af = *(const short8*)&a_row[16 * w + l16][8 * q];
            #pragma unroll
            for (int nt = 0; nt < NT_D; ++nt) {
                short8 bf = *(const short8*)&sTj[16 * nt + l16][32 * jc + 8 * q];
                acc1[nt] = __builtin_amdgcn_mfma_f32_16x16x32_bf16(af, bf, acc1[nt], 0, 0, 0);
            }
        }

        // ---- case 2: s_in for this chunk's 32 j's (complete over i in-block) ----
        {
            f32x4 acc2 = zero;
            #pragma unroll
            for (int ks = 0; ks < 4; ++ks) {
                short8 af = *(const short8*)&aTt[16 * slot_mt + l16][32 * ks + 8 * q];
                short8 bf = *(const short8*)&sTi[16 * slot_nt + l16][32 * ks + 8 * q];
                acc2 = __builtin_amdgcn_mfma_f32_16x16x32_bf16(af, bf, acc2, 0, 0, 0);
            }
            int d = 16 * slot_nt + l16;
            if (d < D) {
                #pragma unroll
                for (int r = 0; r < 4; ++r) {
                    int gj = J0 + 32 * jc + 16 * slot_mt + 4 * q + r;
                    atomicAdd(&out_sin[(size_t)gj * D + d], acc2[r]);
                }
            }
            if (extra) {
                f32x4 acc3 = zero;
                #pragma unroll
                for (int ks = 0; ks < 4; ++ks) {
                    short8 af = *(const short8*)&aTt[16 * w + l16][32 * ks + 8 * q];
                    short8 bf = *(const short8*)&sTi[64 + l16][32 * ks + 8 * q];
                    acc3 = __builtin_amdgcn_mfma_f32_16x16x32_bf16(af, bf, acc3, 0, 0, 0);
                }
                int d2 = 64 + l16;
                if (d2 < D) {
                    #pragma unroll
                    for (int r = 0; r < 4; ++r) {
                        int gj = J0 + 32 * jc + 16 * w + 4 * q + r;
                        atomicAdd(&out_sin[(size_t)gj * D + d2], acc3[r]);
                    }
                }
            }
        }
    }

    // ---- case-1 epilogue: atomic partial s_out ----
    #pragma unroll
    for (int nt = 0; nt < NT_D; ++nt) {
        int d = 16 * nt + l16;
        if (d < D) {
            #pragma unroll
            for (int r = 0; r < 4; ++r) {
                int gi = I0 + 16 * w + 4 * q + r;
                atomicAdd(&out_sout[(size_t)gi * D + d], acc1[nt][r]);
            }
        }
    }
}

// ---------------------------------------------------------------------------
extern "C" void kernel_launch(void* const* d_in, const int* in_sizes, int n_in,
                              void* d_out, int out_size, void* d_ws, size_t ws_size,
                              hipStream_t stream) {
    const float* adj = (const float*)d_in[0];
    const float* s   = (const float*)d_in[1];
    float* out = (float*)d_out;
    unsigned short* sT = (unsigned short*)d_ws;   // needs 80*4096*2 = 655,360 B

    // outputs are accumulated with atomics; harness poisons d_out -> zero it
    hipMemsetAsync(d_out, 0, (size_t)2 * N * D * sizeof(float), stream);

    build_sT<<<dim3(N / 256), dim3(256), 0, stream>>>(s, sT);

    fused_slayer<<<dim3(N / TILE, N / TILE), dim3(512), 0, stream>>>(
        adj, sT, out /*s_in*/, out + (size_t)N * D /*s_out*/);
}

// Round 2
// 229.829 us; speedup vs baseline: 1.2373x; 1.2373x over previous
//
#include <hip/hip_runtime.h>

// CalculateSLayer: a = adj.sum(axis=2) (4096x4096), s_in = a^T @ s, s_out = a @ s.
// Round 2: atomics (102 MB HBM write-through, 138 us) replaced by workspace
// partials + reduction kernel. ws partials should stay L3-resident.
// d_out = [s_in (4096x70) | s_out (4096x70)] fp32.

#define N    4096
#define D    70
#define DP   80          // d padded to 5 n-tiles of 16 (rows 70..79 of sT are zero)
#define TILE 128         // block tile (i) x (j)
#define NT_D 5
#define NPART 32         // N/TILE partials per output element

typedef short short8 __attribute__((ext_vector_type(8)));   // 8 x bf16 bits
typedef float f32x4  __attribute__((ext_vector_type(4)));

__device__ __forceinline__ unsigned short f2bf(float f) {
    unsigned u = __builtin_bit_cast(unsigned, f);
    u += 0x7FFFu + ((u >> 16) & 1u);
    return (unsigned short)(u >> 16);
}

// ---------------------------------------------------------------------------
// kernel0: sT[d][n] = bf16(s[n][d]) for d<70, zeros for 70<=d<80 (in d_ws).
// ---------------------------------------------------------------------------
__global__ __launch_bounds__(256) void build_sT(const float* __restrict__ s,
                                                unsigned short* __restrict__ sT) {
    __shared__ unsigned short tile[DP][264];
    const int t  = threadIdx.x;
    const int n0 = blockIdx.x * 256;
    #pragma unroll
    for (int d = 0; d < D; ++d)
        tile[d][t] = f2bf(s[(size_t)(n0 + t) * D + d]);
    __syncthreads();
    #pragma unroll
    for (int d = 0; d < DP; ++d) {
        unsigned short v = (d < D) ? tile[d][t] : (unsigned short)0;
        sT[(size_t)d * N + n0 + t] = v;
    }
}

// ---------------------------------------------------------------------------
// kernel1: per 128x128 tile of a, compute s_out partial (case 1, contract j)
// and s_in finals-over-block-i (case 2, contract i) with mfma_f32_16x16x32_bf16.
// USE_WS=true : plain stores to ws partials (no atomics).
// USE_WS=false: legacy atomicAdd fallback (only if ws_size too small).
// Layouts (verified, learn_hip m89/m120):
//   A-frag: A[m=lane&15][k=quad*8+j]   B-frag: B[k=quad*8+j][n=lane&15]
//   C/D   : col=lane&15, row=quad*4+reg
// ---------------------------------------------------------------------------
template<bool USE_WS>
__global__ __launch_bounds__(512, 4) void fused_slayer(
    const float* __restrict__ adj,
    const unsigned short* __restrict__ sT,
    float* __restrict__ p_in,     // USE_WS: ws_in[32][N][80]   else out_sin[N][70]
    float* __restrict__ p_out)    // USE_WS: ws_out[32][N][80]  else out_sout[N][70]
{
    __shared__ __align__(16) unsigned short a_row[TILE][40]; // [i][j_local<32]
    __shared__ __align__(16) unsigned short aTt[32][136];    // [j_local][i<128]
    __shared__ __align__(16) unsigned short sTi[DP][136];    // s rows for i-range
    __shared__ __align__(16) unsigned short sTj[DP][136];    // s rows for j-range

    const int t    = threadIdx.x;
    const int lane = t & 63;
    const int w    = t >> 6;       // wave 0..7
    const int l16  = lane & 15;
    const int q    = lane >> 4;    // quad 0..3

    const int I0 = blockIdx.y * TILE;
    const int J0 = blockIdx.x * TILE;

    // ---- stage both s-tiles (bf16 row copies from precomputed sT) ----
    {
        const int c  = t & 15;
        const int rr = t >> 4;
        #pragma unroll
        for (int p = 0; p < 3; ++p) {
            int d = rr + 32 * p;
            if (d < DP) {
                uint4 vi = *(const uint4*)(sT + (size_t)d * N + I0 + 8 * c);
                uint4 vj = *(const uint4*)(sT + (size_t)d * N + J0 + 8 * c);
                *(uint4*)&sTi[d][8 * c] = vi;
                *(uint4*)&sTj[d][8 * c] = vj;
            }
        }
    }

    const f32x4 zero = {0.0f, 0.0f, 0.0f, 0.0f};
    f32x4 acc1[NT_D];
    #pragma unroll
    for (int nt = 0; nt < NT_D; ++nt) acc1[nt] = zero;

    // case-2 slot assignment: 10 slots = 2 m-tiles x 5 n-tiles over 8 waves;
    // waves 0,1 take the extra (mt=w, nt=4) slot.
    const int slot_mt = w & 1;
    const int slot_nt = w >> 1;
    const bool extra  = (w < 2);

    const int jp = t & 15;   // j-pair within 32-wide chunk
    const int ir = t >> 4;   // 0..31

    for (int jc = 0; jc < 4; ++jc) {
        float4 v[4];
        #pragma unroll
        for (int it = 0; it < 4; ++it) {
            int i = 32 * it + ir;
            v[it] = *(const float4*)(adj + (size_t)(I0 + i) * (2 * N)
                                         + (size_t)(J0 + 32 * jc + 2 * jp) * 2);
        }
        __syncthreads();

        #pragma unroll
        for (int it = 0; it < 4; ++it) {
            int i = 32 * it + ir;
            unsigned short b0 = f2bf(v[it].x + v[it].y);
            unsigned short b1 = f2bf(v[it].z + v[it].w);
            *(unsigned int*)&a_row[i][2 * jp] =
                (unsigned int)b0 | ((unsigned int)b1 << 16);
            aTt[2 * jp][i]     = b0;
            aTt[2 * jp + 1][i] = b1;
        }
        __syncthreads();

        // ---- case 1: s_out += a_tile @ s_j ----
        {
            short8 af = *(const short8*)&a_row[16 * w + l16][8 * q];
            #pragma unroll
            for (int nt = 0; nt < NT_D; ++nt) {
                short8 bf = *(const short8*)&sTj[16 * nt + l16][32 * jc + 8 * q];
                acc1[nt] = __builtin_amdgcn_mfma_f32_16x16x32_bf16(af, bf, acc1[nt], 0, 0, 0);
            }
        }

        // ---- case 2: s_in finals for this chunk's 32 j's ----
        {
            f32x4 acc2 = zero;
            #pragma unroll
            for (int ks = 0; ks < 4; ++ks) {
                short8 af = *(const short8*)&aTt[16 * slot_mt + l16][32 * ks + 8 * q];
                short8 bf = *(const short8*)&sTi[16 * slot_nt + l16][32 * ks + 8 * q];
                acc2 = __builtin_amdgcn_mfma_f32_16x16x32_bf16(af, bf, acc2, 0, 0, 0);
            }
            int d = 16 * slot_nt + l16;
            #pragma unroll
            for (int r = 0; r < 4; ++r) {
                int gj = J0 + 32 * jc + 16 * slot_mt + 4 * q + r;
                if (USE_WS) {
                    p_in[((size_t)blockIdx.y * N + gj) * DP + d] = acc2[r];
                } else if (d < D) {
                    atomicAdd(&p_in[(size_t)gj * D + d], acc2[r]);
                }
            }
            if (extra) {
                f32x4 acc3 = zero;
                #pragma unroll
                for (int ks = 0; ks < 4; ++ks) {
                    short8 af = *(const short8*)&aTt[16 * w + l16][32 * ks + 8 * q];
                    short8 bf = *(const short8*)&sTi[64 + l16][32 * ks + 8 * q];
                    acc3 = __builtin_amdgcn_mfma_f32_16x16x32_bf16(af, bf, acc3, 0, 0, 0);
                }
                int d2 = 64 + l16;
                #pragma unroll
                for (int r = 0; r < 4; ++r) {
                    int gj = J0 + 32 * jc + 16 * w + 4 * q + r;
                    if (USE_WS) {
                        p_in[((size_t)blockIdx.y * N + gj) * DP + d2] = acc3[r];
                    } else if (d2 < D) {
                        atomicAdd(&p_in[(size_t)gj * D + d2], acc3[r]);
                    }
                }
            }
        }
    }

    // ---- case-1 epilogue: s_out partial for this block's i-range ----
    #pragma unroll
    for (int nt = 0; nt < NT_D; ++nt) {
        int d = 16 * nt + l16;
        #pragma unroll
        for (int r = 0; r < 4; ++r) {
            int gi = I0 + 16 * w + 4 * q + r;
            if (USE_WS) {
                p_out[((size_t)blockIdx.x * N + gi) * DP + d] = acc1[nt][r];
            } else if (d < D) {
                atomicAdd(&p_out[(size_t)gi * D + d], acc1[nt][r]);
            }
        }
    }
}

// ---------------------------------------------------------------------------
// kernel2: reduce 32 partials -> out. ws layout: [which][part<32][N][80] f32.
// One thread per (which, j, 4-d group); grid 640 x 256 covers 2*4096*20 groups.
// ---------------------------------------------------------------------------
__global__ __launch_bounds__(256) void reduce_partials(
    const float* __restrict__ ws, float* __restrict__ out) {
    const int idx   = blockIdx.x * 256 + threadIdx.x;      // 0 .. 163839
    const int which = idx / (N * (DP / 4));
    const int rem   = idx % (N * (DP / 4));
    const int j     = rem / (DP / 4);
    const int g     = rem % (DP / 4);

    const float* base = ws + (size_t)which * ((size_t)NPART * N * DP)
                           + (size_t)j * DP + 4 * g;
    f32x4 s0 = {0,0,0,0}, s1 = {0,0,0,0}, s2 = {0,0,0,0}, s3 = {0,0,0,0};
    #pragma unroll
    for (int p = 0; p < NPART; p += 4) {
        s0 += *(const f32x4*)(base + (size_t)(p + 0) * N * DP);
        s1 += *(const f32x4*)(base + (size_t)(p + 1) * N * DP);
        s2 += *(const f32x4*)(base + (size_t)(p + 2) * N * DP);
        s3 += *(const f32x4*)(base + (size_t)(p + 3) * N * DP);
    }
    f32x4 s = (s0 + s1) + (s2 + s3);

    float* o = out + (size_t)which * (N * D) + (size_t)j * D;
    #pragma unroll
    for (int e = 0; e < 4; ++e) {
        int d = 4 * g + e;
        if (d < D) o[d] = s[e];
    }
}

// ---------------------------------------------------------------------------
extern "C" void kernel_launch(void* const* d_in, const int* in_sizes, int n_in,
                              void* d_out, int out_size, void* d_ws, size_t ws_size,
                              hipStream_t stream) {
    const float* adj = (const float*)d_in[0];
    const float* s   = (const float*)d_in[1];
    float* out = (float*)d_out;

    unsigned short* sT = (unsigned short*)d_ws;              // 80*4096*2 = 655,360 B
    const size_t ST_BYTES = (size_t)DP * N * sizeof(unsigned short);
    float* ws_part = (float*)((char*)d_ws + ST_BYTES);       // [2][32][N][80] f32
    const size_t PART_FLOATS = (size_t)NPART * N * DP;       // per output
    const size_t NEED = ST_BYTES + 2 * PART_FLOATS * sizeof(float); // ~84.5 MB

    build_sT<<<dim3(N / 256), dim3(256), 0, stream>>>(s, sT);

    if (ws_size >= NEED) {
        // partials path: no atomics, no output memset needed (stage 2 writes all)
        fused_slayer<true><<<dim3(N / TILE, N / TILE), dim3(512), 0, stream>>>(
            adj, sT, ws_part /*ws_in*/, ws_part + PART_FLOATS /*ws_out*/);
        reduce_partials<<<dim3(2 * N * (DP / 4) / 256), dim3(256), 0, stream>>>(
            ws_part, out);
    } else {
        // fallback: legacy atomic path
        hipMemsetAsync(d_out, 0, (size_t)2 * N * D * sizeof(float), stream);
        fused_slayer<false><<<dim3(N / TILE, N / TILE), dim3(512), 0, stream>>>(
            adj, sT, out /*s_in*/, out + (size_t)N * D /*s_out*/);
    }
}

// Round 3
// 212.134 us; speedup vs baseline: 1.3406x; 1.0834x over previous
//
#include <hip/hip_runtime.h>

// CalculateSLayer: a = adj.sum(axis=2) (4096x4096), s_in = a^T @ s, s_out = a @ s.
// Round 3: bf16 ws partials (84->42 MB), software-pipelined global prefetch
// (chunk jc+1 loads in flight during chunk jc MFMA), aTt pitch 132 (bank
// conflicts 8-way -> 4-way, frag reads as 2x ds_read_b64).
// d_out = [s_in (4096x70) | s_out (4096x70)] fp32.

#define N    4096
#define D    70
#define DP   80          // d padded to 5 n-tiles of 16 (rows 70..79 of sT are zero)
#define TILE 128         // block tile (i) x (j)
#define NT_D 5
#define NPART 32         // N/TILE partials per output element
#define ATP  132         // aTt pitch: 264B rows, 8B-aligned (b64), 4-way write conflicts

typedef short short8  __attribute__((ext_vector_type(8)));   // 8 x bf16 bits
typedef short short4v __attribute__((ext_vector_type(4)));
typedef float f32x4   __attribute__((ext_vector_type(4)));

__device__ __forceinline__ unsigned short f2bf(float f) {
    unsigned u = __builtin_bit_cast(unsigned, f);
    u += 0x7FFFu + ((u >> 16) & 1u);
    return (unsigned short)(u >> 16);
}
__device__ __forceinline__ float bf2f(unsigned short h) {
    unsigned u = (unsigned)h << 16;
    return __builtin_bit_cast(float, u);
}
__device__ __forceinline__ short8 ld_b64x2(const unsigned short* p) {
    short4v lo = *(const short4v*)p;        // 8B aligned
    short4v hi = *(const short4v*)(p + 4);
    return __builtin_shufflevector(lo, hi, 0, 1, 2, 3, 4, 5, 6, 7);
}

// ---------------------------------------------------------------------------
// kernel0: sT[d][n] = bf16(s[n][d]) for d<70, zeros for 70<=d<80 (in d_ws).
// ---------------------------------------------------------------------------
__global__ __launch_bounds__(256) void build_sT(const float* __restrict__ s,
                                                unsigned short* __restrict__ sT) {
    __shared__ unsigned short tile[DP][264];
    const int t  = threadIdx.x;
    const int n0 = blockIdx.x * 256;
    #pragma unroll
    for (int d = 0; d < D; ++d)
        tile[d][t] = f2bf(s[(size_t)(n0 + t) * D + d]);
    __syncthreads();
    #pragma unroll
    for (int d = 0; d < DP; ++d) {
        unsigned short v = (d < D) ? tile[d][t] : (unsigned short)0;
        sT[(size_t)d * N + n0 + t] = v;
    }
}

// ---------------------------------------------------------------------------
// kernel1: per 128x128 tile of a, s_out partial (case 1, contract j) and
// s_in finals-over-block-i (case 2, contract i), mfma_f32_16x16x32_bf16.
// USE_WS=true : bf16 partial stores to ws.  false: legacy f32 atomics to out.
// Layouts (verified, learn_hip m89/m120):
//   A-frag: A[m=lane&15][k=quad*8+j]   B-frag: B[k=quad*8+j][n=lane&15]
//   C/D   : col=lane&15, row=quad*4+reg
// ---------------------------------------------------------------------------
template<bool USE_WS>
__global__ __launch_bounds__(512, 4) void fused_slayer(
    const float* __restrict__ adj,
    const unsigned short* __restrict__ sT,
    void* __restrict__ p_in_,     // USE_WS: ushort ws_in[32][N][80] else float out_sin
    void* __restrict__ p_out_)    // USE_WS: ushort ws_out[32][N][80] else float out_sout
{
    unsigned short* wi = (unsigned short*)p_in_;
    unsigned short* wo = (unsigned short*)p_out_;
    float* oi = (float*)p_in_;
    float* oo = (float*)p_out_;

    __shared__ __align__(16) unsigned short a_row[TILE][40]; // [i][j_local<32]
    __shared__ __align__(16) unsigned short aTt[32][ATP];    // [j_local][i<128]
    __shared__ __align__(16) unsigned short sTi[DP][136];    // s rows for i-range
    __shared__ __align__(16) unsigned short sTj[DP][136];    // s rows for j-range

    const int t    = threadIdx.x;
    const int lane = t & 63;
    const int w    = t >> 6;       // wave 0..7
    const int l16  = lane & 15;
    const int q    = lane >> 4;    // quad 0..3

    const int I0 = blockIdx.y * TILE;
    const int J0 = blockIdx.x * TILE;

    // ---- stage both s-tiles (bf16 row copies from precomputed sT) ----
    {
        const int c  = t & 15;
        const int rr = t >> 4;
        #pragma unroll
        for (int p = 0; p < 3; ++p) {
            int d = rr + 32 * p;
            if (d < DP) {
                uint4 vi = *(const uint4*)(sT + (size_t)d * N + I0 + 8 * c);
                uint4 vj = *(const uint4*)(sT + (size_t)d * N + J0 + 8 * c);
                *(uint4*)&sTi[d][8 * c] = vi;
                *(uint4*)&sTj[d][8 * c] = vj;
            }
        }
    }

    const f32x4 zero = {0.0f, 0.0f, 0.0f, 0.0f};
    f32x4 acc1[NT_D];
    #pragma unroll
    for (int nt = 0; nt < NT_D; ++nt) acc1[nt] = zero;

    // case-2 slot assignment: 10 slots = 2 m-tiles x 5 n-tiles over 8 waves;
    // waves 0,1 take the extra (mt=w, nt=4) slot.
    const int slot_mt = w & 1;
    const int slot_nt = w >> 1;
    const bool extra  = (w < 2);

    const int jp = t & 15;   // j-pair within 32-wide chunk
    const int ir = t >> 4;   // 0..31

    // ---- preload chunk 0 ----
    float4 v[4];
    #pragma unroll
    for (int it = 0; it < 4; ++it) {
        int i = 32 * it + ir;
        v[it] = *(const float4*)(adj + (size_t)(I0 + i) * (2 * N)
                                     + (size_t)(J0 + 2 * jp) * 2);
    }

    #pragma unroll
    for (int jc = 0; jc < 4; ++jc) {
        __syncthreads();   // previous chunk's LDS reads complete

        #pragma unroll
        for (int it = 0; it < 4; ++it) {
            int i = 32 * it + ir;
            unsigned short b0 = f2bf(v[it].x + v[it].y);   // a = ch0 + ch1
            unsigned short b1 = f2bf(v[it].z + v[it].w);
            *(unsigned int*)&a_row[i][2 * jp] =
                (unsigned int)b0 | ((unsigned int)b1 << 16);
            aTt[2 * jp][i]     = b0;   // 4-way-conflict b16 transpose stores
            aTt[2 * jp + 1][i] = b1;
        }
        __syncthreads();

        // prefetch chunk jc+1 (overlaps MFMA + partial stores + next barrier)
        if (jc < 3) {
            #pragma unroll
            for (int it = 0; it < 4; ++it) {
                int i = 32 * it + ir;
                v[it] = *(const float4*)(adj + (size_t)(I0 + i) * (2 * N)
                                             + (size_t)(J0 + 32 * (jc + 1) + 2 * jp) * 2);
            }
        }

        // ---- case 1: s_out += a_tile @ s_j ----
        {
            short8 af = *(const short8*)&a_row[16 * w + l16][8 * q];
            #pragma unroll
            for (int nt = 0; nt < NT_D; ++nt) {
                short8 bf = *(const short8*)&sTj[16 * nt + l16][32 * jc + 8 * q];
                acc1[nt] = __builtin_amdgcn_mfma_f32_16x16x32_bf16(af, bf, acc1[nt], 0, 0, 0);
            }
        }

        // ---- case 2: s_in finals for this chunk's 32 j's ----
        {
            f32x4 acc2 = zero;
            #pragma unroll
            for (int ks = 0; ks < 4; ++ks) {
                short8 af = ld_b64x2(&aTt[16 * slot_mt + l16][32 * ks + 8 * q]);
                short8 bf = *(const short8*)&sTi[16 * slot_nt + l16][32 * ks + 8 * q];
                acc2 = __builtin_amdgcn_mfma_f32_16x16x32_bf16(af, bf, acc2, 0, 0, 0);
            }
            int d = 16 * slot_nt + l16;
            #pragma unroll
            for (int r = 0; r < 4; ++r) {
                int gj = J0 + 32 * jc + 16 * slot_mt + 4 * q + r;
                if (USE_WS) {
                    wi[((size_t)blockIdx.y * N + gj) * DP + d] = f2bf(acc2[r]);
                } else if (d < D) {
                    atomicAdd(&oi[(size_t)gj * D + d], acc2[r]);
                }
            }
            if (extra) {
                f32x4 acc3 = zero;
                #pragma unroll
                for (int ks = 0; ks < 4; ++ks) {
                    short8 af = ld_b64x2(&aTt[16 * w + l16][32 * ks + 8 * q]);
                    short8 bf = *(const short8*)&sTi[64 + l16][32 * ks + 8 * q];
                    acc3 = __builtin_amdgcn_mfma_f32_16x16x32_bf16(af, bf, acc3, 0, 0, 0);
                }
                int d2 = 64 + l16;
                #pragma unroll
                for (int r = 0; r < 4; ++r) {
                    int gj = J0 + 32 * jc + 16 * w + 4 * q + r;
                    if (USE_WS) {
                        wi[((size_t)blockIdx.y * N + gj) * DP + d2] = f2bf(acc3[r]);
                    } else if (d2 < D) {
                        atomicAdd(&oi[(size_t)gj * D + d2], acc3[r]);
                    }
                }
            }
        }
    }

    // ---- case-1 epilogue: s_out partial for this block's i-range ----
    #pragma unroll
    for (int nt = 0; nt < NT_D; ++nt) {
        int d = 16 * nt + l16;
        #pragma unroll
        for (int r = 0; r < 4; ++r) {
            int gi = I0 + 16 * w + 4 * q + r;
            if (USE_WS) {
                wo[((size_t)blockIdx.x * N + gi) * DP + d] = f2bf(acc1[nt][r]);
            } else if (d < D) {
                atomicAdd(&oo[(size_t)gi * D + d], acc1[nt][r]);
            }
        }
    }
}

// ---------------------------------------------------------------------------
// kernel2: reduce 32 bf16 partials -> f32 out.
// ws layout: ushort [which][part<32][N][80]. One thread per (which, j, 8-d
// group); 2*4096*10 = 81920 threads; 128-thread blocks -> 640 blocks.
// ---------------------------------------------------------------------------
__global__ __launch_bounds__(128) void reduce_partials(
    const unsigned short* __restrict__ ws, float* __restrict__ out) {
    const int idx   = blockIdx.x * 128 + threadIdx.x;      // 0 .. 81919
    const int which = idx / (N * (DP / 8));
    const int rem   = idx % (N * (DP / 8));
    const int j     = rem / (DP / 8);
    const int g     = rem % (DP / 8);

    const unsigned short* base = ws + (size_t)which * ((size_t)NPART * N * DP)
                                    + (size_t)j * DP + 8 * g;
    float acc[8];
    #pragma unroll
    for (int e = 0; e < 8; ++e) acc[e] = 0.0f;
    #pragma unroll 8
    for (int p = 0; p < NPART; ++p) {
        short8 v = *(const short8*)(base + (size_t)p * N * DP);
        #pragma unroll
        for (int e = 0; e < 8; ++e)
            acc[e] += bf2f((unsigned short)v[e]);
    }

    float* o = out + (size_t)which * (N * D) + (size_t)j * D;
    #pragma unroll
    for (int e = 0; e < 8; ++e) {
        int d = 8 * g + e;
        if (d < D) o[d] = acc[e];
    }
}

// ---------------------------------------------------------------------------
extern "C" void kernel_launch(void* const* d_in, const int* in_sizes, int n_in,
                              void* d_out, int out_size, void* d_ws, size_t ws_size,
                              hipStream_t stream) {
    const float* adj = (const float*)d_in[0];
    const float* s   = (const float*)d_in[1];
    float* out = (float*)d_out;

    unsigned short* sT = (unsigned short*)d_ws;              // 80*4096*2 = 655,360 B
    const size_t ST_BYTES = (size_t)DP * N * sizeof(unsigned short);
    unsigned short* ws_part = (unsigned short*)((char*)d_ws + ST_BYTES);
    const size_t PART_ELEMS = (size_t)NPART * N * DP;        // per output
    const size_t NEED = ST_BYTES + 2 * PART_ELEMS * sizeof(unsigned short); // ~42.6 MB

    build_sT<<<dim3(N / 256), dim3(256), 0, stream>>>(s, sT);

    if (ws_size >= NEED) {
        fused_slayer<true><<<dim3(N / TILE, N / TILE), dim3(512), 0, stream>>>(
            adj, sT, ws_part /*ws_in*/, ws_part + PART_ELEMS /*ws_out*/);
        reduce_partials<<<dim3(2 * N * (DP / 8) / 128), dim3(128), 0, stream>>>(
            ws_part, out);
    } else {
        hipMemsetAsync(d_out, 0, (size_t)2 * N * D * sizeof(float), stream);
        fused_slayer<false><<<dim3(N / TILE, N / TILE), dim3(512), 0, stream>>>(
            adj, sT, out /*s_in*/, out + (size_t)N * D /*s_out*/);
    }
}